// Round 8
// baseline (880.868 us; speedup 1.0000x reference)
//
#include <hip/hip_runtime.h>
#include <hip/hip_bf16.h>

#define TOKENS 16384
#define DMODEL 2048
#define NEXP   64
#define KWIN   32
#define TPBLK  128     // tokens per block
#define NTHR   128     // 2 waves

// out layout (floats): probs[T*2] | indices[T*2] | tokens_per_expert[64] | aux[1]
#define OFF_IDX  (TOKENS * 2)
#define OFF_HIST (TOKENS * 4)
#define OFF_AUX  (TOKENS * 4 + NEXP)

#define XPAD 36
#define WPAD 36

// Wave-wide (lane=expert) softmax + top-2 epilogue for one token. Validated in R1-R7.
__device__ __forceinline__ void token_epilogue(float v, int lane, int tok,
                                               float* __restrict__ out,
                                               int* hist_s, float& local_psum)
{
    float m = v;
#pragma unroll
    for (int off = 32; off; off >>= 1) m = fmaxf(m, __shfl_xor(m, off));
    float ex = __expf(v - m);
    float S = ex;
#pragma unroll
    for (int off = 32; off; off >>= 1) S += __shfl_xor(S, off);
    local_psum += ex / S;

    float bv = v; int bi = lane;
#pragma unroll
    for (int off = 32; off; off >>= 1) {
        float ov = __shfl_xor(bv, off);
        int   oi = __shfl_xor(bi, off);
        if (ov > bv || (ov == bv && oi < bi)) { bv = ov; bi = oi; }
    }
    float v1 = bv; int i1 = bi;
    float bv2 = (lane == i1) ? -3.4e38f : v; int bi2 = lane;
#pragma unroll
    for (int off = 32; off; off >>= 1) {
        float ov = __shfl_xor(bv2, off);
        int   oi = __shfl_xor(bi2, off);
        if (ov > bv2 || (ov == bv2 && oi < bi2)) { bv2 = ov; bi2 = oi; }
    }
    float v2 = bv2; int i2 = bi2;

    if (lane == 0) {
        float e1 = __expf(v1 - m);
        float e2 = __expf(v2 - m);
        float inv = 1.f / (e1 + e2);
        out[tok * 2 + 0] = e1 * inv;
        out[tok * 2 + 1] = e2 * inv;
        out[OFF_IDX + tok * 2 + 0] = (float)i1;
        out[OFF_IDX + tok * 2 + 1] = (float)i2;
        atomicAdd(&hist_s[i1], 1);
        atomicAdd(&hist_s[i2], 1);
    }
}

// Block GEMM: 128 tok x 64 exp, thread-tile 8x8, K-range [kbase, kbase+nwin*32).
// FUSED=false: write partial logits to partial[blockIdx.y][tok][e].
// FUSED=true (nsplit==1): in-kernel epilogue via LDS exchange.
template<bool FUSED>
__global__ __launch_bounds__(NTHR, 2) void gemm_kernel(
    const float* __restrict__ x,      // [T, D]
    const float* __restrict__ gw,     // [E, D]
    float* __restrict__ partial,      // [nsplit][T][64]
    float* __restrict__ out,
    float* __restrict__ probsum_g,
    float* __restrict__ hist_g,
    int nwin)
{
    __shared__ float X_lds[TPBLK][XPAD];   // 18.4 KB
    __shared__ float W_lds[NEXP][WPAD];    // 9.2 KB
    __shared__ float psum_s[2][NEXP];
    __shared__ int   hist_s[NEXP];

    const int tid  = threadIdx.x;
    const int wave = tid >> 6;
    const int lane = tid & 63;
    const int tg   = tid >> 3;   // token group 0..15
    const int eg   = tid & 7;    // expert group 0..7
    const int rb   = tid >> 3;   // staging row base
    const int c4   = tid & 7;    // staging col (float4 idx)
    const int tok0 = blockIdx.x * TPBLK;
    const int kbase = blockIdx.y * (nwin * KWIN);

    if (FUSED && tid < NEXP) hist_s[tid] = 0;

    float acc[8][8];
#pragma unroll
    for (int i = 0; i < 8; ++i)
#pragma unroll
        for (int j = 0; j < 8; ++j) acc[i][j] = 0.f;

    float4 xr[8], wr[4];

    auto LOADG = [&](int k0) __attribute__((always_inline)) {
#pragma unroll
        for (int i = 0; i < 8; ++i)
            xr[i] = *(const float4*)&x[(size_t)(tok0 + rb + 16 * i) * DMODEL + k0 + c4 * 4];
#pragma unroll
        for (int i = 0; i < 4; ++i)
            wr[i] = *(const float4*)&gw[(size_t)(rb + 16 * i) * DMODEL + k0 + c4 * 4];
    };
    auto WRITE = [&]() __attribute__((always_inline)) {
#pragma unroll
        for (int i = 0; i < 8; ++i) *(float4*)&X_lds[rb + 16 * i][c4 * 4] = xr[i];
#pragma unroll
        for (int i = 0; i < 4; ++i) *(float4*)&W_lds[rb + 16 * i][c4 * 4] = wr[i];
    };
    auto COMPUTE = [&]() __attribute__((always_inline)) {
#pragma unroll
        for (int q = 0; q < 8; ++q) {
            float4 xa[8], wb[8];
#pragma unroll
            for (int i = 0; i < 8; ++i) xa[i] = *(const float4*)&X_lds[tg * 8 + i][q * 4];
#pragma unroll
            for (int j = 0; j < 8; ++j) wb[j] = *(const float4*)&W_lds[eg * 8 + j][q * 4];
#pragma unroll
            for (int i = 0; i < 8; ++i)
#pragma unroll
                for (int j = 0; j < 8; ++j) {
                    acc[i][j] = fmaf(xa[i].x, wb[j].x, acc[i][j]);
                    acc[i][j] = fmaf(xa[i].y, wb[j].y, acc[i][j]);
                    acc[i][j] = fmaf(xa[i].z, wb[j].z, acc[i][j]);
                    acc[i][j] = fmaf(xa[i].w, wb[j].w, acc[i][j]);
                }
        }
    };

    LOADG(kbase);
    WRITE();
    __syncthreads();
    for (int w = 0; w < nwin; ++w) {
        if (w + 1 < nwin) LOADG(kbase + (w + 1) * KWIN);   // reg-prefetch (T14)
        COMPUTE();
        __syncthreads();                                   // done reading window w
        if (w + 1 < nwin) { WRITE(); __syncthreads(); }
    }

    if (!FUSED) {
        float* po = partial + ((size_t)blockIdx.y * TOKENS + tok0) * NEXP;
#pragma unroll
        for (int i = 0; i < 8; ++i) {
#pragma unroll
            for (int jq = 0; jq < 2; ++jq)
                *(float4*)&po[(size_t)(tg * 8 + i) * NEXP + eg * 8 + jq * 4] =
                    make_float4(acc[i][jq * 4 + 0], acc[i][jq * 4 + 1],
                                acc[i][jq * 4 + 2], acc[i][jq * 4 + 3]);
        }
        return;
    }

    // ---- FUSED epilogue: exchange logits through X_lds (reused as ls[64][64]) ----
    float* ls = &X_lds[0][0];   // 64 x 64 tile, two half-passes
    float local_psum = 0.f;
#pragma unroll
    for (int p = 0; p < 2; ++p) {
        __syncthreads();
        if ((tg >> 3) == p) {
            int tr = tg & 7;
#pragma unroll
            for (int i = 0; i < 8; ++i)
#pragma unroll
                for (int jq = 0; jq < 2; ++jq)
                    *(float4*)&ls[(tr * 8 + i) * 64 + eg * 8 + jq * 4] =
                        make_float4(acc[i][jq * 4 + 0], acc[i][jq * 4 + 1],
                                    acc[i][jq * 4 + 2], acc[i][jq * 4 + 3]);
        }
        __syncthreads();
        for (int t = 0; t < 32; ++t) {
            int tl  = wave * 32 + t;
            int tok = tok0 + p * 64 + tl;
            token_epilogue(ls[tl * 64 + lane], lane, tok, out, hist_s, local_psum);
        }
    }
    psum_s[wave][lane] = local_psum;
    __syncthreads();
    if (wave == 0) {
        float s = psum_s[0][lane] + psum_s[1][lane];
        atomicAdd(&probsum_g[lane], s);
        atomicAdd(&hist_g[lane], (float)hist_s[lane]);
    }
}

// Split-K reduce + softmax + top-2 + hist. 512 blocks x 256 thr; wave = 8 tokens.
__global__ __launch_bounds__(256) void finalize_kernel(
    const float* __restrict__ partial, int nsplit,
    float* __restrict__ out,
    float* __restrict__ probsum_g, float* __restrict__ hist_g)
{
    __shared__ float psum_s[4][NEXP];
    __shared__ int   hist_s[NEXP];

    const int tid  = threadIdx.x;
    const int wave = tid >> 6;
    const int lane = tid & 63;
    if (tid < NEXP) hist_s[tid] = 0;
    __syncthreads();

    float local_psum = 0.f;
#pragma unroll
    for (int t = 0; t < 8; ++t) {
        int tok = blockIdx.x * 32 + wave * 8 + t;
        float v = 0.f;
        for (int s = 0; s < nsplit; ++s)
            v += partial[((size_t)s * TOKENS + tok) * NEXP + lane];
        token_epilogue(v, lane, tok, out, hist_s, local_psum);
    }

    psum_s[wave][lane] = local_psum;
    __syncthreads();
    if (wave == 0) {
        float s = psum_s[0][lane] + psum_s[1][lane] + psum_s[2][lane] + psum_s[3][lane];
        atomicAdd(&probsum_g[lane], s);
        atomicAdd(&hist_g[lane], (float)hist_s[lane]);
    }
}

__global__ void aux_kernel(const float* __restrict__ probsum_g,
                           const float* __restrict__ hist_g,
                           float* __restrict__ out)
{
    int e = threadIdx.x;  // 64 threads
    float tpe = hist_g[e];
    out[OFF_HIST + e] = tpe;
    const float invT = 1.f / (float)TOKENS;
    float term = (tpe * invT) * (probsum_g[e] * invT);
#pragma unroll
    for (int off = 32; off; off >>= 1) term += __shfl_xor(term, off);
    if (e == 0) out[OFF_AUX] = term * (float)NEXP;
}

extern "C" void kernel_launch(void* const* d_in, const int* in_sizes, int n_in,
                              void* d_out, int out_size, void* d_ws, size_t ws_size,
                              hipStream_t stream) {
    const float* x  = (const float*)d_in[0];
    const float* gw = (const float*)d_in[1];
    float* out = (float*)d_out;
    float* ws  = (float*)d_ws;

    const size_t per = (size_t)TOKENS * NEXP * sizeof(float);   // 4 MB per split
    int nsplit = 0;
    if      (ws_size >= 8 * per + 512) nsplit = 8;
    else if (ws_size >= 4 * per + 512) nsplit = 4;
    else if (ws_size >= 2 * per + 512) nsplit = 2;
    else if (ws_size >= 1 * per + 512) nsplit = 1;

    if (nsplit > 0) {
        float* partial = ws;
        float* accw    = ws + (size_t)nsplit * TOKENS * NEXP;   // probsum[64] | hist[64]
        (void)hipMemsetAsync(accw, 0, 128 * sizeof(float), stream);
        int nwin = (DMODEL / KWIN) / nsplit;                    // 8/16/32/64
        gemm_kernel<false><<<dim3(TOKENS / TPBLK, nsplit), NTHR, 0, stream>>>(
            x, gw, partial, nullptr, nullptr, nullptr, nwin);
        finalize_kernel<<<dim3(TOKENS / 32), 256, 0, stream>>>(
            partial, nsplit, out, accw, accw + NEXP);
        aux_kernel<<<1, 64, 0, stream>>>(accw, accw + NEXP, out);
    } else {
        float* accw = ws;   // needs only 512 B
        (void)hipMemsetAsync(accw, 0, 128 * sizeof(float), stream);
        gemm_kernel<true><<<dim3(TOKENS / TPBLK, 1), NTHR, 0, stream>>>(
            x, gw, nullptr, out, accw, accw + NEXP, DMODEL / KWIN);
        aux_kernel<<<1, 64, 0, stream>>>(accw, accw + NEXP, out);
    }
}

// Round 9
// 744.453 us; speedup vs baseline: 1.1832x; 1.1832x over previous
//
#include <hip/hip_runtime.h>
#include <hip/hip_bf16.h>

#define TOKENS 16384
#define DMODEL 2048
#define NEXP   64
#define KWIN   32
#define BM     256     // tokens per block
#define NTHR   256     // 4 waves

// out layout (floats): probs[T*2] | indices[T*2] | tokens_per_expert[64] | aux[1]
#define OFF_IDX  (TOKENS * 2)
#define OFF_HIST (TOKENS * 4)
#define OFF_AUX  (TOKENS * 4 + NEXP)

// Wave-wide (lane=expert) softmax + top-2 epilogue for one token. Validated R1-R8.
__device__ __forceinline__ void token_epilogue(float v, int lane, int tok,
                                               float* __restrict__ out,
                                               int* hist_s, float& local_psum)
{
    float m = v;
#pragma unroll
    for (int off = 32; off; off >>= 1) m = fmaxf(m, __shfl_xor(m, off));
    float ex = __expf(v - m);
    float S = ex;
#pragma unroll
    for (int off = 32; off; off >>= 1) S += __shfl_xor(S, off);
    local_psum += ex / S;

    float bv = v; int bi = lane;
#pragma unroll
    for (int off = 32; off; off >>= 1) {
        float ov = __shfl_xor(bv, off);
        int   oi = __shfl_xor(bi, off);
        if (ov > bv || (ov == bv && oi < bi)) { bv = ov; bi = oi; }
    }
    float v1 = bv; int i1 = bi;
    float bv2 = (lane == i1) ? -3.4e38f : v; int bi2 = lane;
#pragma unroll
    for (int off = 32; off; off >>= 1) {
        float ov = __shfl_xor(bv2, off);
        int   oi = __shfl_xor(bi2, off);
        if (ov > bv2 || (ov == bv2 && oi < bi2)) { bv2 = ov; bi2 = oi; }
    }
    float v2 = bv2; int i2 = bi2;

    if (lane == 0) {
        float e1 = __expf(v1 - m);
        float e2 = __expf(v2 - m);
        float inv = 1.f / (e1 + e2);
        out[tok * 2 + 0] = e1 * inv;
        out[tok * 2 + 1] = e2 * inv;
        out[OFF_IDX + tok * 2 + 0] = (float)i1;
        out[OFF_IDX + tok * 2 + 1] = (float)i2;
        atomicAdd(&hist_s[i1], 1);
        atomicAdd(&hist_s[i2], 1);
    }
}

// 256tok x 64exp block GEMM, thread-tile 8x8. W staged in LDS (pad 33, 2-way max);
// X read per-lane from global (8 eg lanes share each address -> TA coalesces).
__global__ __launch_bounds__(NTHR, 2) void gemm_kernel(
    const float* __restrict__ x,      // [T, D]
    const float* __restrict__ gw,     // [E, D]
    float* __restrict__ partial,      // [nsplit][T][64]
    int nwin)
{
    __shared__ float W_lds[2][NEXP][33];   // 16.9 KB

    const int tid  = threadIdx.x;
    const int lane = tid & 63;
    const int tg   = (tid >> 6) * 8 + (lane >> 3);  // 0..31 token group
    const int eg   = lane & 7;                      // 0..7 expert group
    const int tok0 = blockIdx.x * BM;
    const int kbase = blockIdx.y * nwin * KWIN;
    const int qmax  = nwin * 8 - 1;

    // W staging map: e = tid>>2 (0..63), two float4 at cols sc*4 and sc*4+16
    const int se = tid >> 2;
    const int sc = tid & 3;
    const float* wg = gw + (size_t)se * DMODEL + kbase + sc * 4;

    float acc[8][8];
#pragma unroll
    for (int i = 0; i < 8; ++i)
#pragma unroll
        for (int j = 0; j < 8; ++j) acc[i][j] = 0.f;

    const float* xr[8];
#pragma unroll
    for (int i = 0; i < 8; ++i)
        xr[i] = x + (size_t)(tok0 + tg * 8 + i) * DMODEL + kbase;

    float4 XA[8], XB[8], w0, w1;

    auto LX = [&](float4* B, int q) __attribute__((always_inline)) {
#pragma unroll
        for (int i = 0; i < 8; ++i) B[i] = *(const float4*)(xr[i] + (size_t)q * 4);
    };
    auto LW = [&](int w) __attribute__((always_inline)) {
        const float* g = wg + (size_t)w * KWIN;
        w0 = *(const float4*)(g);
        w1 = *(const float4*)(g + 16);
    };
    auto SW = [&](int b) __attribute__((always_inline)) {
        *(float4*)&W_lds[b][se][sc * 4]      = w0;
        *(float4*)&W_lds[b][se][sc * 4 + 16] = w1;
    };
    auto STEP = [&](float4* B, int buf, int qq) __attribute__((always_inline)) {
        float4 wf[8];
#pragma unroll
        for (int jj = 0; jj < 8; ++jj)
            wf[jj] = *(const float4*)&W_lds[buf][eg * 8 + jj][qq * 4];
#pragma unroll
        for (int i = 0; i < 8; ++i)
#pragma unroll
            for (int jj = 0; jj < 8; ++jj) {
                acc[i][jj] = fmaf(B[i].x, wf[jj].x, acc[i][jj]);
                acc[i][jj] = fmaf(B[i].y, wf[jj].y, acc[i][jj]);
                acc[i][jj] = fmaf(B[i].z, wf[jj].z, acc[i][jj]);
                acc[i][jj] = fmaf(B[i].w, wf[jj].w, acc[i][jj]);
            }
    };

    LW(0); SW(0);
    if (nwin > 1) LW(1);
    LX(XA, 0); LX(XB, 1);
    __syncthreads();

    for (int w = 0; w < nwin; ++w) {
        const int q0 = w * 8, buf = w & 1;
        STEP(XA, buf, 0); LX(XA, min(q0 + 2, qmax));
        STEP(XB, buf, 1); LX(XB, min(q0 + 3, qmax));
        STEP(XA, buf, 2); LX(XA, min(q0 + 4, qmax));
        STEP(XB, buf, 3); LX(XB, min(q0 + 5, qmax));
        STEP(XA, buf, 4); LX(XA, min(q0 + 6, qmax));
        STEP(XB, buf, 5); LX(XB, min(q0 + 7, qmax));
        STEP(XA, buf, 6); LX(XA, min(q0 + 8, qmax));
        STEP(XB, buf, 7); LX(XB, min(q0 + 9, qmax));
        if (w + 1 < nwin) { SW(buf ^ 1); if (w + 2 < nwin) LW(w + 2); }
        __syncthreads();
    }

    float* po = partial + ((size_t)blockIdx.y * TOKENS + tok0 + tg * 8) * NEXP + eg * 8;
#pragma unroll
    for (int i = 0; i < 8; ++i) {
        *(float4*)&po[(size_t)i * NEXP + 0] =
            make_float4(acc[i][0], acc[i][1], acc[i][2], acc[i][3]);
        *(float4*)&po[(size_t)i * NEXP + 4] =
            make_float4(acc[i][4], acc[i][5], acc[i][6], acc[i][7]);
    }
}

// Split-K reduce + softmax + top-2 + hist. 512 blocks x 256 thr; wave = 8 tokens.
__global__ __launch_bounds__(256) void finalize_kernel(
    const float* __restrict__ partial, int nsplit,
    float* __restrict__ out,
    float* __restrict__ probsum_g, float* __restrict__ hist_g)
{
    __shared__ float psum_s[4][NEXP];
    __shared__ int   hist_s[NEXP];

    const int tid  = threadIdx.x;
    const int wave = tid >> 6;
    const int lane = tid & 63;
    if (tid < NEXP) hist_s[tid] = 0;
    __syncthreads();

    float local_psum = 0.f;
#pragma unroll
    for (int t = 0; t < 8; ++t) {
        int tok = blockIdx.x * 32 + wave * 8 + t;
        float v = 0.f;
        for (int s = 0; s < nsplit; ++s)
            v += partial[((size_t)s * TOKENS + tok) * NEXP + lane];
        token_epilogue(v, lane, tok, out, hist_s, local_psum);
    }

    psum_s[wave][lane] = local_psum;
    __syncthreads();
    if (wave == 0) {
        float s = psum_s[0][lane] + psum_s[1][lane] + psum_s[2][lane] + psum_s[3][lane];
        atomicAdd(&probsum_g[lane], s);
        atomicAdd(&hist_g[lane], (float)hist_s[lane]);
    }
}

// Small-ws fallback: round-1 kernel (validated, ~210us). lane=expert, 8 tok/wave.
__global__ __launch_bounds__(256) void fallback_kernel(
    const float* __restrict__ x, const float* __restrict__ gw,
    float* __restrict__ out,
    float* __restrict__ probsum_g, float* __restrict__ hist_g)
{
    __shared__ float xs[32][64];
    __shared__ float wt[64][NEXP + 1];
    __shared__ float psum_s[4][NEXP];
    __shared__ int   hist_s[NEXP];

    const int tid  = threadIdx.x;
    const int wave = tid >> 6;
    const int lane = tid & 63;
    const int tok0 = blockIdx.x * 32;
    if (tid < NEXP) hist_s[tid] = 0;

    float acc[8];
#pragma unroll
    for (int t = 0; t < 8; ++t) acc[t] = 0.f;

    for (int k0 = 0; k0 < DMODEL; k0 += 64) {
        __syncthreads();
#pragma unroll
        for (int i = 0; i < 2; ++i) {
            int idx = tid + i * 256;
            int r = idx >> 4, c = idx & 15;
            *(float4*)&xs[r][c * 4] = *(const float4*)&x[(size_t)(tok0 + r) * DMODEL + k0 + c * 4];
        }
#pragma unroll
        for (int i = 0; i < 4; ++i) {
            int idx = tid + i * 256;
            int e = idx >> 4, c = idx & 15;
            float4 v = *(const float4*)&gw[(size_t)e * DMODEL + k0 + c * 4];
            wt[c * 4 + 0][e] = v.x; wt[c * 4 + 1][e] = v.y;
            wt[c * 4 + 2][e] = v.z; wt[c * 4 + 3][e] = v.w;
        }
        __syncthreads();
#pragma unroll
        for (int kk4 = 0; kk4 < 16; ++kk4) {
            float w0 = wt[kk4 * 4 + 0][lane], w1 = wt[kk4 * 4 + 1][lane];
            float w2 = wt[kk4 * 4 + 2][lane], w3 = wt[kk4 * 4 + 3][lane];
#pragma unroll
            for (int t = 0; t < 8; ++t) {
                float4 xv = *(const float4*)&xs[wave * 8 + t][kk4 * 4];
                acc[t] = fmaf(xv.x, w0, acc[t]); acc[t] = fmaf(xv.y, w1, acc[t]);
                acc[t] = fmaf(xv.z, w2, acc[t]); acc[t] = fmaf(xv.w, w3, acc[t]);
            }
        }
    }
    float local_psum = 0.f;
#pragma unroll
    for (int t = 0; t < 8; ++t)
        token_epilogue(acc[t], lane, tok0 + wave * 8 + t, out, hist_s, local_psum);
    psum_s[wave][lane] = local_psum;
    __syncthreads();
    if (wave == 0) {
        float s = psum_s[0][lane] + psum_s[1][lane] + psum_s[2][lane] + psum_s[3][lane];
        atomicAdd(&probsum_g[lane], s);
        atomicAdd(&hist_g[lane], (float)hist_s[lane]);
    }
}

__global__ void aux_kernel(const float* __restrict__ probsum_g,
                           const float* __restrict__ hist_g,
                           float* __restrict__ out)
{
    int e = threadIdx.x;  // 64 threads
    float tpe = hist_g[e];
    out[OFF_HIST + e] = tpe;
    const float invT = 1.f / (float)TOKENS;
    float term = (tpe * invT) * (probsum_g[e] * invT);
#pragma unroll
    for (int off = 32; off; off >>= 1) term += __shfl_xor(term, off);
    if (e == 0) out[OFF_AUX] = term * (float)NEXP;
}

extern "C" void kernel_launch(void* const* d_in, const int* in_sizes, int n_in,
                              void* d_out, int out_size, void* d_ws, size_t ws_size,
                              hipStream_t stream) {
    const float* x  = (const float*)d_in[0];
    const float* gw = (const float*)d_in[1];
    float* out = (float*)d_out;
    float* ws  = (float*)d_ws;

    const size_t per = (size_t)TOKENS * NEXP * sizeof(float);   // 4 MB per split
    int nsplit = 0;
    if      (ws_size >= 8 * per + 512) nsplit = 8;
    else if (ws_size >= 4 * per + 512) nsplit = 4;
    else if (ws_size >= 2 * per + 512) nsplit = 2;
    else if (ws_size >= 1 * per + 512) nsplit = 1;

    if (nsplit > 0) {
        float* partial = ws;
        float* accw    = ws + (size_t)nsplit * TOKENS * NEXP;   // probsum[64] | hist[64]
        (void)hipMemsetAsync(accw, 0, 128 * sizeof(float), stream);
        int nwin = (DMODEL / KWIN) / nsplit;                    // 8/16/32/64
        gemm_kernel<<<dim3(TOKENS / BM, nsplit), NTHR, 0, stream>>>(x, gw, partial, nwin);
        finalize_kernel<<<dim3(TOKENS / 32), 256, 0, stream>>>(
            partial, nsplit, out, accw, accw + NEXP);
        aux_kernel<<<1, 64, 0, stream>>>(accw, accw + NEXP, out);
    } else {
        float* accw = ws;   // needs only 512 B
        (void)hipMemsetAsync(accw, 0, 128 * sizeof(float), stream);
        fallback_kernel<<<dim3(TOKENS / 32), 256, 0, stream>>>(x, gw, out, accw, accw + NEXP);
        aux_kernel<<<1, 64, 0, stream>>>(accw, accw + NEXP, out);
    }
}